// Round 3
// baseline (10086.065 us; speedup 1.0000x reference)
//
#include <hip/hip_runtime.h>
#include <math.h>

#define VOCAB 32000
#define H 256
#define BATCH 16
#define T 512
#define NT 6
#define START 4
#define STOP 5
#define NEGV -10000.0f

// ws layout (floats):
// [0, 262144)              WihT  [256][1024]  (k-major transpose of W_ih)
// [262144, 262144+8388608) Xp    [B*T][1024]  (input projections + bias)

__global__ void transpose_wih(const float* __restrict__ W_ih, float* __restrict__ WihT) {
    int o = blockIdx.x * blockDim.x + threadIdx.x;
    if (o >= 256 * 1024) return;
    int k = o >> 10;
    int g = o & 1023;
    WihT[o] = W_ih[g * 256 + k];
}

// One block = 16 (b,t) rows, 1024 threads = 1 thread per gate.
__global__ __launch_bounds__(1024) void input_proj(const int* __restrict__ sentence,
                                                   const float* __restrict__ embedding,
                                                   const float* __restrict__ WihT,
                                                   const float* __restrict__ b_ih,
                                                   const float* __restrict__ b_hh,
                                                   float* __restrict__ Xp) {
    __shared__ __align__(16) float emb[16][260];  // row stride 260*4=1040B (16B aligned)
    int tid = threadIdx.x;
    int bt0 = blockIdx.x * 16;
    {
        int r = tid >> 6, j = tid & 63;
        int row = sentence[bt0 + r];
        const float4* src = (const float4*)(embedding + (size_t)row * 256);
        float4 v = src[j];
        float* dst = &emb[r][j * 4];
        dst[0] = v.x; dst[1] = v.y; dst[2] = v.z; dst[3] = v.w;
    }
    __syncthreads();
    int g = tid;
    float bias = b_ih[g] + b_hh[g];
    float acc[16];
#pragma unroll
    for (int r = 0; r < 16; r++) acc[r] = bias;
    const float* wp = WihT + g;
    for (int k4 = 0; k4 < 64; k4++) {
        float w0 = wp[(k4 * 4 + 0) * 1024];
        float w1 = wp[(k4 * 4 + 1) * 1024];
        float w2 = wp[(k4 * 4 + 2) * 1024];
        float w3 = wp[(k4 * 4 + 3) * 1024];
#pragma unroll
        for (int r = 0; r < 16; r++) {
            float4 e = *(const float4*)&emb[r][k4 * 4];
            acc[r] += w0 * e.x + w1 * e.y + w2 * e.z + w3 * e.w;
        }
    }
#pragma unroll
    for (int r = 0; r < 16; r++) Xp[(size_t)(bt0 + r) * 1024 + g] = acc[r];
}

// X-macro: 64 named float4 registers for this thread's W_hh row (gate column).
// Named SSA values (NO array, NO alloca) -> guaranteed register allocation.
#define REP64(X) \
    X(0) X(1) X(2) X(3) X(4) X(5) X(6) X(7) X(8) X(9) X(10) X(11) X(12) X(13) X(14) X(15) \
    X(16) X(17) X(18) X(19) X(20) X(21) X(22) X(23) X(24) X(25) X(26) X(27) X(28) X(29) X(30) X(31) \
    X(32) X(33) X(34) X(35) X(36) X(37) X(38) X(39) X(40) X(41) X(42) X(43) X(44) X(45) X(46) X(47) \
    X(48) X(49) X(50) X(51) X(52) X(53) X(54) X(55) X(56) X(57) X(58) X(59) X(60) X(61) X(62) X(63)

// One block per batch element. 1024 threads = 1 per gate. W_hh in registers
// (64 named float4/thread, loaded from row-major W_hh = contiguous 16B/lane).
// __launch_bounds__(1024,4): 16-wave block, 1 block/CU -> VGPR budget 512.
__global__ __launch_bounds__(1024, 4) void lstm_crf(const float* __restrict__ W_hh,
                                                    const float* __restrict__ Xp,
                                                    const float* __restrict__ W_out,
                                                    const float* __restrict__ b_out,
                                                    const float* __restrict__ trans,
                                                    float* __restrict__ out) {
    __shared__ __align__(16) float h_lds[256];
    __shared__ float gates_lds[1024];
    __shared__ __align__(16) float wout_lds[6 * 256];
    __shared__ float feat_lds[6];
    __shared__ float trans_lds[36];
    __shared__ unsigned bp_lds[512];

    int tid = threadIdx.x;
    int b = blockIdx.x;

    // hoist this thread's W_hh row (gate tid) into 64 named float4 registers
    const float4* wrow = (const float4*)(W_hh + (size_t)tid * 256);
#define DECL_W(i) float4 w##i = wrow[i];
    REP64(DECL_W)
#undef DECL_W

    if (tid < 256) h_lds[tid] = 0.f;
    for (int i = tid; i < 6 * 256; i += 1024) wout_lds[i] = W_out[i];
    if (tid < 36) trans_lds[tid] = trans[tid];
    float c_reg = 0.f;
    float fv[6];
    if (tid == 0) {
#pragma unroll
        for (int i = 0; i < 6; i++) fv[i] = (i == START) ? 0.f : NEGV;
    }
    __syncthreads();

    const float* xp = Xp + (size_t)b * T * 1024 + tid;
    float x_cur = xp[0];
    const float4* hbc = (const float4*)h_lds;

    for (int t = 0; t < T; t++) {
        // prefetch next step's input projection (hides HBM/L2 latency under the dot)
        float x_next = (t + 1 < T) ? xp[(size_t)(t + 1) * 1024] : 0.f;

        // Phase 1: gates = Xp + h . w (length-256 dot; h broadcast b128 from LDS,
        // same-address across lanes = conflict-free broadcast)
        float acc = x_cur;
#define DOT(i) { float4 hv = hbc[i]; acc += w##i.x * hv.x + w##i.y * hv.y + w##i.z * hv.z + w##i.w * hv.w; }
        REP64(DOT)
#undef DOT
        int gtype = tid >> 8;  // 0:i 1:f 2:g 3:o
        float val = (gtype == 2) ? tanhf(acc) : 1.f / (1.f + expf(-acc));
        gates_lds[tid] = val;   // safe: previous step's gates reads finished before barrier B(t-1) < C(t-1)
        __syncthreads();  // A: gates ready; also orders h reads (phase 1) before h overwrite (phase 2)

        // Phase 2: c/h update
        if (tid < 256) {
            float iv = gates_lds[tid];
            float fg = gates_lds[256 + tid];
            float gv = gates_lds[512 + tid];
            float ov = gates_lds[768 + tid];
            c_reg = fg * c_reg + iv * gv;
            h_lds[tid] = ov * tanhf(c_reg);
        }
        __syncthreads();  // B: h_t ready

        // Phase 3: feats[w] = h . W_out[w] + b_out[w], one wave per tag
        if (tid < 384) {
            int w = tid >> 6, lane = tid & 63;
            float4 hh = *(const float4*)&h_lds[lane * 4];
            float4 ww = *(const float4*)&wout_lds[w * 256 + lane * 4];
            float p = hh.x * ww.x + hh.y * ww.y + hh.z * ww.z + hh.w * ww.w;
#pragma unroll
            for (int off = 32; off; off >>= 1) p += __shfl_down(p, off);
            if (lane == 0) feat_lds[w] = p + b_out[w];
        }
        __syncthreads();  // C: feats ready

        // Phase 4: CRF forward step (thread 0), overlaps others' next phase-1
        if (tid == 0) {
            unsigned packed = 0;
            float nfv[6];
#pragma unroll
            for (int nx = 0; nx < 6; nx++) {
                float best = fv[0] + trans_lds[nx * 6 + 0];
                int arg = 0;
#pragma unroll
                for (int pv = 1; pv < 6; pv++) {
                    float s = fv[pv] + trans_lds[nx * 6 + pv];
                    if (s > best) { best = s; arg = pv; }  // strict >: first-max like np.argmax
                }
                nfv[nx] = best + feat_lds[nx];
                packed |= (unsigned)arg << (3 * nx);
            }
#pragma unroll
            for (int i = 0; i < 6; i++) fv[i] = nfv[i];
            bp_lds[t] = packed;
        }
        x_cur = x_next;
    }

    // Terminal + backtrack
    if (tid == 0) {
        float best = fv[0] + trans_lds[STOP * 6 + 0];
        int arg = 0;
#pragma unroll
        for (int tg = 1; tg < 6; tg++) {
            float s = fv[tg] + trans_lds[STOP * 6 + tg];
            if (s > best) { best = s; arg = tg; }
        }
        out[b] = best;  // path score
        int tag = arg;
        float* paths = out + 16 + (size_t)b * 512;
        for (int t = T - 1; t >= 0; t--) {
            paths[t] = (float)tag;
            tag = (bp_lds[t] >> (3 * tag)) & 7;
        }
    }
}

extern "C" void kernel_launch(void* const* d_in, const int* in_sizes, int n_in,
                              void* d_out, int out_size, void* d_ws, size_t ws_size,
                              hipStream_t stream) {
    const int* sentence = (const int*)d_in[0];
    const float* embedding = (const float*)d_in[1];
    const float* W_ih = (const float*)d_in[2];
    const float* W_hh = (const float*)d_in[3];
    const float* b_ih = (const float*)d_in[4];
    const float* b_hh = (const float*)d_in[5];
    const float* W_out = (const float*)d_in[6];
    const float* b_out = (const float*)d_in[7];
    const float* trans = (const float*)d_in[8];
    float* out = (float*)d_out;
    float* ws = (float*)d_ws;

    float* WihT = ws;
    float* Xp = ws + 262144;

    hipLaunchKernelGGL(transpose_wih, dim3(1024), dim3(256), 0, stream, W_ih, WihT);
    hipLaunchKernelGGL(input_proj, dim3(BATCH * T / 16), dim3(1024), 0, stream,
                       sentence, embedding, WihT, b_ih, b_hh, Xp);
    hipLaunchKernelGGL(lstm_crf, dim3(BATCH), dim3(1024), 0, stream,
                       W_hh, Xp, W_out, b_out, trans, out);
}

// Round 4
// 4255.385 us; speedup vs baseline: 2.3702x; 2.3702x over previous
//
#include <hip/hip_runtime.h>
#include <math.h>

#define HDIM 256
#define BATCH 16
#define T 512
#define NT 6
#define START 4
#define STOP 5
#define NEGV -10000.0f
#define LOG2E 1.4426950408889634f

typedef __attribute__((ext_vector_type(8))) short short8;
typedef __attribute__((ext_vector_type(4))) float f32x4;

__device__ __forceinline__ float fast_sig(float x) {
    float e = __builtin_amdgcn_exp2f(-LOG2E * x);
    return __builtin_amdgcn_rcpf(1.f + e);
}
__device__ __forceinline__ float fast_tanh(float x) {
    float e = __builtin_amdgcn_exp2f(-2.f * LOG2E * x);
    return (1.f - e) * __builtin_amdgcn_rcpf(1.f + e);
}
__device__ __forceinline__ unsigned short bf16_rne(float f) {
    unsigned u = __builtin_bit_cast(unsigned, f);
    u += 0x7FFFu + ((u >> 16) & 1u);
    return (unsigned short)(u >> 16);
}

// ws layout (bytes):
//   [0, 32MB)        Xp2  fp32 [t][w][n][lane][j]  (input projections, exact fp32)
//                    ... ALSO aliased by H bf16 [t][u][b] during lstm_mfma:
//                    H[t] (8KB/step) writes trail Xp2[t] (64KB/step) reads by 8x -> safe.
//   [32MB, 33MB)     WihT fp32 (pre-lstm only) -- aliased by Wf bf16 frags [32MB,32.5MB)

__global__ void transpose_wih(const float* __restrict__ W_ih, float* __restrict__ WihT) {
    int o = blockIdx.x * blockDim.x + threadIdx.x;
    if (o >= 256 * 1024) return;
    int k = o >> 10;
    int g = o & 1023;
    WihT[o] = W_ih[g * 256 + k];
}

// Pack W_hh (fp32 [1024][256]) into bf16 MFMA B-fragments.
// flat frag id f = ((w*4+n)*8+kt); lane l: g = n*256 + w*16 + (l&15), k = kt*32 + (l>>4)*8 + j
__global__ void wf_prep(const float* __restrict__ W_hh, unsigned short* __restrict__ Wf) {
    int t = blockIdx.x * 256 + threadIdx.x;  // 0..32767
    int l = t & 63, kt = (t >> 6) & 7, n = (t >> 9) & 3, w = t >> 11;
    int g = n * 256 + w * 16 + (l & 15);
    int kk = kt * 32 + (l >> 4) * 8;
    const float* src = W_hh + g * 256 + kk;
    unsigned short* dst = Wf + (size_t)t * 8;
#pragma unroll
    for (int j = 0; j < 8; j++) dst[j] = bf16_rne(src[j]);
}

// One block = 16 (b,t) rows (same b, 16 consecutive t), 1024 threads = 1 per gate.
// Writes Xp2 in the MFMA C-layout: [t][w][n][lane=q*16+c][j] fp32.
__global__ __launch_bounds__(1024) void input_proj(const int* __restrict__ sentence,
                                                   const float* __restrict__ embedding,
                                                   const float* __restrict__ WihT,
                                                   const float* __restrict__ b_ih,
                                                   const float* __restrict__ b_hh,
                                                   float* __restrict__ Xp2) {
    __shared__ __align__(16) float emb[16][260];
    int tid = threadIdx.x;
    int bt0 = blockIdx.x * 16;
    {
        int r = tid >> 6, j = tid & 63;
        int row = sentence[bt0 + r];
        const float4* src = (const float4*)(embedding + (size_t)row * 256);
        float4 v = src[j];
        float* dst = &emb[r][j * 4];
        dst[0] = v.x; dst[1] = v.y; dst[2] = v.z; dst[3] = v.w;
    }
    __syncthreads();
    int g = tid;
    float bias = b_ih[g] + b_hh[g];
    float acc[16];
#pragma unroll
    for (int r = 0; r < 16; r++) acc[r] = bias;
    const float* wp = WihT + g;
    for (int k4 = 0; k4 < 64; k4++) {
        float w0 = wp[(k4 * 4 + 0) * 1024];
        float w1 = wp[(k4 * 4 + 1) * 1024];
        float w2 = wp[(k4 * 4 + 2) * 1024];
        float w3 = wp[(k4 * 4 + 3) * 1024];
#pragma unroll
        for (int r = 0; r < 16; r++) {
            float4 e = *(const float4*)&emb[r][k4 * 4];
            acc[r] += w0 * e.x + w1 * e.y + w2 * e.z + w3 * e.w;
        }
    }
    int b = bt0 >> 9, t0 = bt0 & 511;
    int q = b >> 2, j = b & 3;
    int n = g >> 8, u = g & 255, w = u >> 4, cc = u & 15;
    int lane = q * 16 + cc;
#pragma unroll
    for (int r = 0; r < 16; r++) {
        int t = t0 + r;
        Xp2[(size_t)(((t * 16 + w) * 4 + n) * 64 + lane) * 4 + j] = acc[r];
    }
}

// ONE block, 1024 threads (16 waves), one CU. Per step: [16,256]x[256,1024] bf16 MFMA.
// Wave w owns gate columns {n*256 + w*16 + c} for n=i,f,g,o -> c,h update fully in-register.
__global__ __attribute__((amdgpu_flat_work_group_size(1024, 1024), amdgpu_waves_per_eu(4, 4)))
void lstm_mfma(const unsigned short* __restrict__ Wf, const float* __restrict__ Xp2,
               unsigned short* __restrict__ Hg) {
    __shared__ unsigned short h_sw[BATCH * HDIM];  // 8KB bf16, XOR-swizzled
    int tid = threadIdx.x;
    int w = tid >> 6, l = tid & 63;
    int q = l >> 4, c = l & 15;

    // B-fragments of W_hh: 32 x short8 = 128 VGPR (coalesced 16B/lane loads)
    short8 wr[4][8];
#pragma unroll
    for (int n = 0; n < 4; n++)
#pragma unroll
        for (int kt = 0; kt < 8; kt++)
            wr[n][kt] = *(const short8*)(Wf + (size_t)((((w * 4 + n) * 8) + kt) * 64 + l) * 8);

    // A-frag LDS byte offsets (swizzle: byte(b,u) = b*512 + ((2u) ^ ((b&7)<<4)))
    int bA = c;
    int xorv = (bA & 7) << 4;
    int a_off[8];
#pragma unroll
    for (int kt = 0; kt < 8; kt++) a_off[kt] = bA * 512 + ((kt * 64 + q * 16) ^ xorv);

    // h write offsets: this lane owns (b = q*4+j, u = w*16+c)
    int u = w * 16 + c;
    int wb[4];
#pragma unroll
    for (int j = 0; j < 4; j++) {
        int bj = q * 4 + j;
        wb[j] = bj * 512 + ((u * 2) ^ ((bj & 7) << 4));
    }

    // zero h(t=-1)
    *(uint2*)((char*)h_sw + tid * 8) = make_uint2(0, 0);

    float cst[4] = {0.f, 0.f, 0.f, 0.f};
    const char* xptr = (const char*)Xp2 + (w * 4) * 1024 + l * 16;
    f32x4 xv[4];
#pragma unroll
    for (int n = 0; n < 4; n++) xv[n] = *(const f32x4*)(xptr + n * 1024);
    xptr += 65536;
    unsigned short* hptr = Hg + u * 16 + q * 4;  // H[t][u][b] bf16, t-stride 4096 ushorts
    __syncthreads();

    for (int t = 0; t < T; t++) {
        f32x4 acc[4];
#pragma unroll
        for (int n = 0; n < 4; n++) acc[n] = xv[n];
        // prefetch t+1 (at t=511 reads into WihT/Wf region: in-bounds of ws, unused)
#pragma unroll
        for (int n = 0; n < 4; n++) xv[n] = *(const f32x4*)(xptr + n * 1024);
        xptr += 65536;

        short8 af[8];
#pragma unroll
        for (int kt = 0; kt < 8; kt++)
            af[kt] = *(const short8*)((const char*)h_sw + a_off[kt]);
#pragma unroll
        for (int kt = 0; kt < 8; kt++)
#pragma unroll
            for (int n = 0; n < 4; n++)
                acc[n] = __builtin_amdgcn_mfma_f32_16x16x32_bf16(af[kt], wr[n][kt], acc[n], 0, 0, 0);

        unsigned short hb[4];
#pragma unroll
        for (int j = 0; j < 4; j++) {
            float iv = fast_sig(acc[0][j]);
            float fg = fast_sig(acc[1][j]);
            float gv = fast_tanh(acc[2][j]);
            float ov = fast_sig(acc[3][j]);
            cst[j] = fg * cst[j] + iv * gv;
            hb[j] = bf16_rne(ov * fast_tanh(cst[j]));
        }
        __syncthreads();  // all A-reads of h(t-1) done before overwrite
#pragma unroll
        for (int j = 0; j < 4; j++) *(unsigned short*)((char*)h_sw + wb[j]) = hb[j];
        // global h history for the viterbi kernel: 4 consecutive b at (t,u)
        uint2 hp;
        hp.x = (unsigned)hb[0] | ((unsigned)hb[1] << 16);
        hp.y = (unsigned)hb[2] | ((unsigned)hb[3] << 16);
        *(uint2*)hptr = hp;
        hptr += 4096;
        __syncthreads();  // h(t) visible for step t+1
    }
}

// 16 blocks (one per batch), 384 threads = 6 waves, wave = tag.
__global__ __launch_bounds__(384) void viterbi(const unsigned short* __restrict__ Hg,
                                               const float* __restrict__ W_out,
                                               const float* __restrict__ b_out,
                                               const float* __restrict__ trans,
                                               float* __restrict__ out) {
    __shared__ float wout_s[6 * 256];
    __shared__ float trans_s[36];
    __shared__ float feat_s[6];
    __shared__ unsigned bp_lds[512];
    int tid = threadIdx.x, b = blockIdx.x;
    int tag = tid >> 6, lane = tid & 63;
    for (int i = tid; i < 6 * 256; i += 384) wout_s[i] = W_out[i];
    if (tid < 36) trans_s[tid] = trans[tid];
    float fv[6];
#pragma unroll
    for (int i = 0; i < 6; i++) fv[i] = (i == START) ? 0.f : NEGV;
    __syncthreads();

    for (int t = 0; t < T; t++) {
        float p = 0.f;
#pragma unroll
        for (int m = 0; m < 4; m++) {
            int uu = m * 64 + lane;
            float h = __builtin_bit_cast(float, ((unsigned)Hg[(size_t)(t * 256 + uu) * 16 + b]) << 16);
            p += h * wout_s[tag * 256 + uu];
        }
#pragma unroll
        for (int off = 32; off; off >>= 1) p += __shfl_down(p, off);
        if (lane == 0) feat_s[tag] = p + b_out[tag];
        __syncthreads();
        if (tid == 0) {
            unsigned packed = 0;
            float nfv[6];
#pragma unroll
            for (int nx = 0; nx < 6; nx++) {
                float best = fv[0] + trans_s[nx * 6];
                int arg = 0;
#pragma unroll
                for (int pv = 1; pv < 6; pv++) {
                    float s = fv[pv] + trans_s[nx * 6 + pv];
                    if (s > best) { best = s; arg = pv; }  // strict >: first-max like np.argmax
                }
                nfv[nx] = best + feat_s[nx];
                packed |= (unsigned)arg << (3 * nx);
            }
#pragma unroll
            for (int i = 0; i < 6; i++) fv[i] = nfv[i];
            bp_lds[t] = packed;
        }
        __syncthreads();
    }

    if (tid == 0) {
        float best = fv[0] + trans_s[STOP * 6];
        int arg = 0;
#pragma unroll
        for (int tg = 1; tg < 6; tg++) {
            float s = fv[tg] + trans_s[STOP * 6 + tg];
            if (s > best) { best = s; arg = tg; }
        }
        out[b] = best;
        int tagc = arg;
        float* paths = out + 16 + (size_t)b * 512;
        for (int t = T - 1; t >= 0; t--) {
            paths[t] = (float)tagc;
            tagc = (bp_lds[t] >> (3 * tagc)) & 7;
        }
    }
}

extern "C" void kernel_launch(void* const* d_in, const int* in_sizes, int n_in,
                              void* d_out, int out_size, void* d_ws, size_t ws_size,
                              hipStream_t stream) {
    const int* sentence = (const int*)d_in[0];
    const float* embedding = (const float*)d_in[1];
    const float* W_ih = (const float*)d_in[2];
    const float* W_hh = (const float*)d_in[3];
    const float* b_ih = (const float*)d_in[4];
    const float* b_hh = (const float*)d_in[5];
    const float* W_out = (const float*)d_in[6];
    const float* b_out = (const float*)d_in[7];
    const float* trans = (const float*)d_in[8];
    float* out = (float*)d_out;
    float* ws = (float*)d_ws;

    float* Xp2 = ws;                                   // 32 MB fp32
    unsigned short* Hg = (unsigned short*)ws;          // bf16 h history, aliases Xp2 (safe: 8x trail)
    float* WihT = ws + 8388608;                        // 1 MB, pre-lstm only
    unsigned short* Wf = (unsigned short*)(ws + 8388608);  // 512 KB bf16 frags, aliases WihT after use

    hipLaunchKernelGGL(transpose_wih, dim3(1024), dim3(256), 0, stream, W_ih, WihT);
    hipLaunchKernelGGL(input_proj, dim3(BATCH * T / 16), dim3(1024), 0, stream,
                       sentence, embedding, WihT, b_ih, b_hh, Xp2);
    hipLaunchKernelGGL(wf_prep, dim3(128), dim3(256), 0, stream, W_hh, Wf);
    hipLaunchKernelGGL(lstm_mfma, dim3(1), dim3(1024), 0, stream, Wf, Xp2, Hg);
    hipLaunchKernelGGL(viterbi, dim3(BATCH), dim3(384), 0, stream, Hg, W_out, b_out, trans, out);
}

// Round 5
// 1331.803 us; speedup vs baseline: 7.5732x; 3.1952x over previous
//
#include <hip/hip_runtime.h>
#include <math.h>

#define HDIM 256
#define BATCH 16
#define T 512
#define NT 6
#define START 4
#define STOP 5
#define NEGV -10000.0f
#define LOG2E 1.4426950408889634f
#define NBLK 16  // lstm blocks; block k owns gate cols {n*256 + k*16 + c}

typedef __attribute__((ext_vector_type(8))) short short8;
typedef __attribute__((ext_vector_type(4))) float f32x4;

__device__ __forceinline__ float fast_sig(float x) {
    float e = __builtin_amdgcn_exp2f(-LOG2E * x);
    return __builtin_amdgcn_rcpf(1.f + e);
}
__device__ __forceinline__ float fast_tanh(float x) {
    float e = __builtin_amdgcn_exp2f(-2.f * LOG2E * x);
    return (1.f - e) * __builtin_amdgcn_rcpf(1.f + e);
}
__device__ __forceinline__ unsigned short bf16_rne(float f) {
    unsigned u = __builtin_bit_cast(unsigned, f);
    u += 0x7FFFu + ((u >> 16) & 1u);
    return (unsigned short)(u >> 16);
}

// ws layout (float units):
//   [0, 8388608)            Xp2 fp32 [t][k][n][lane][j]   (32 MB)
//                           ... Hg bf16 [t][k][b][ul] aliases base (4 MB): Hg[t] writes
//                           (8KB/step) trail Xp2[t] reads (64KB/step) by 8x -> never clobber.
//   [8388608, 8650752)      WihT fp32 (dead after input_proj)
//   [8650752, 8781824)      Wf bf16 MFMA B-fragments (512 KB)
//   [8781824, 8830976)      feats fp32 [b][t][6]
//   [8830976, 8831488)      cnt int[512]  (step barrier counters, zeroed each call)

__global__ void transpose_wih(const float* __restrict__ W_ih, float* __restrict__ WihT,
                              int* __restrict__ cnt) {
    int o = blockIdx.x * blockDim.x + threadIdx.x;
    if (o < 512) cnt[o] = 0;
    if (o >= 256 * 1024) return;
    int k = o >> 10;
    int g = o & 1023;
    WihT[o] = W_ih[g * 256 + k];
}

// Pack W_hh (fp32 [1024][256]) into bf16 MFMA B-fragments.
// flat frag f = ((k*4+n)*8+kt); lane l: g = n*256 + k*16 + (l&15), kk = kt*32 + (l>>4)*8 + j
__global__ void wf_prep(const float* __restrict__ W_hh, unsigned short* __restrict__ Wf) {
    int t = blockIdx.x * 256 + threadIdx.x;  // 0..32767
    int l = t & 63, kt = (t >> 6) & 7, n = (t >> 9) & 3, w = t >> 11;
    int g = n * 256 + w * 16 + (l & 15);
    int kk = kt * 32 + (l >> 4) * 8;
    const float* src = W_hh + g * 256 + kk;
    unsigned short* dst = Wf + (size_t)t * 8;
#pragma unroll
    for (int j = 0; j < 8; j++) dst[j] = bf16_rne(src[j]);
}

// One block = 16 (b,t) rows (same b, 16 consecutive t), 1024 threads = 1 per gate.
// Writes Xp2 in the MFMA C-layout: [t][k][n][lane=q*16+c][j] fp32.
__global__ __launch_bounds__(1024) void input_proj(const int* __restrict__ sentence,
                                                   const float* __restrict__ embedding,
                                                   const float* __restrict__ WihT,
                                                   const float* __restrict__ b_ih,
                                                   const float* __restrict__ b_hh,
                                                   float* __restrict__ Xp2) {
    __shared__ __align__(16) float emb[16][260];
    int tid = threadIdx.x;
    int bt0 = blockIdx.x * 16;
    {
        int r = tid >> 6, j = tid & 63;
        int row = sentence[bt0 + r];
        const float4* src = (const float4*)(embedding + (size_t)row * 256);
        float4 v = src[j];
        float* dst = &emb[r][j * 4];
        dst[0] = v.x; dst[1] = v.y; dst[2] = v.z; dst[3] = v.w;
    }
    __syncthreads();
    int g = tid;
    float bias = b_ih[g] + b_hh[g];
    float acc[16];
#pragma unroll
    for (int r = 0; r < 16; r++) acc[r] = bias;
    const float* wp = WihT + g;
    for (int k4 = 0; k4 < 64; k4++) {
        float w0 = wp[(k4 * 4 + 0) * 1024];
        float w1 = wp[(k4 * 4 + 1) * 1024];
        float w2 = wp[(k4 * 4 + 2) * 1024];
        float w3 = wp[(k4 * 4 + 3) * 1024];
#pragma unroll
        for (int r = 0; r < 16; r++) {
            float4 e = *(const float4*)&emb[r][k4 * 4];
            acc[r] += w0 * e.x + w1 * e.y + w2 * e.z + w3 * e.w;
        }
    }
    int b = bt0 >> 9, t0 = bt0 & 511;
    int q = b >> 2, j = b & 3;
    int n = g >> 8, u = g & 255, k = u >> 4, cc = u & 15;
    int lane = q * 16 + cc;
#pragma unroll
    for (int r = 0; r < 16; r++) {
        int t = t0 + r;
        Xp2[(size_t)(((t * 16 + k) * 4 + n) * 64 + lane) * 4 + j] = acc[r];
    }
}

// 16 blocks x 256 threads. Block k owns 64 gate columns (wave n = gate type, 16 cols).
// Weights resident in 32 VGPR/thread. Per step: 8 MFMA -> LDS gate exchange -> c/h ->
// publish h slice (512B) to Hg[t] -> release cnt[t]; next step acquire-spins cnt[t-1]
// then all-gathers h (8KB) from LLC.
__global__ __launch_bounds__(256) void lstm_mfma(const unsigned short* __restrict__ Wf,
                                                 const float* __restrict__ Xp2,
                                                 unsigned short* __restrict__ Hg,
                                                 int* __restrict__ cnt) {
    __shared__ float gl[4][16][16];
    int tid = threadIdx.x;
    int k = blockIdx.x;
    int n = tid >> 6;          // wave = gate type (i,f,g,o)
    int l = tid & 63;
    int q = l >> 4, c = l & 15;

    // B-fragments of this block's W_hh slice: 8 x short8 = 32 VGPR
    short8 wr[8];
#pragma unroll
    for (int kt = 0; kt < 8; kt++)
        wr[kt] = *(const short8*)(Wf + ((size_t)((k * 4 + n) * 8 + kt) * 64 + l) * 8);

    float c_st = 0.f;  // cell state for (b = tid>>4, u = k*16 + (tid&15))

    const char* xbase = (const char*)Xp2 + ((size_t)k * 4 + n) * 1024 + (size_t)l * 16;
    f32x4 xv = *(const f32x4*)xbase;

    // A-frag base within Hg[t] (ushort units): row b=(l&15), u = kt*32 + q*8 + j
    // Hg layout [t][ks][b][ul]: addr = ks*256 + b*16 + ul, ks = u>>4, ul = u&15
    int abase = (q >> 1) * 256 + (l & 15) * 16 + (q & 1) * 8;

    for (int t = 0; t < T; t++) {
        f32x4 xnext = xv;
        if (t + 1 < T) xnext = *(const f32x4*)(xbase + (size_t)(t + 1) * 65536);
        f32x4 acc = xv;
        if (t > 0) {
            if (tid == 0) {
                while (__hip_atomic_load(&cnt[t - 1], __ATOMIC_ACQUIRE,
                                         __HIP_MEMORY_SCOPE_AGENT) < NBLK) { }
            }
            __syncthreads();  // h(t-1) globally visible
            const unsigned short* hsrc = Hg + (size_t)(t - 1) * 4096 + abase;
            short8 af[8];
#pragma unroll
            for (int kt = 0; kt < 8; kt++)
                af[kt] = *(const short8*)(hsrc + kt * 512);
#pragma unroll
            for (int kt = 0; kt < 8; kt++)
                acc = __builtin_amdgcn_mfma_f32_16x16x32_bf16(af[kt], wr[kt], acc, 0, 0, 0);
        }
        // exchange gates across waves: lane (q,c) reg j -> (b=q*4+j, col c), gate n
#pragma unroll
        for (int j = 0; j < 4; j++) gl[n][q * 4 + j][c] = acc[j];
        __syncthreads();
        {
            int b_own = tid >> 4, ul = tid & 15;
            float iv = fast_sig(gl[0][b_own][ul]);
            float fg = fast_sig(gl[1][b_own][ul]);
            float gv = fast_tanh(gl[2][b_own][ul]);
            float ov = fast_sig(gl[3][b_own][ul]);
            c_st = fg * c_st + iv * gv;
            Hg[(size_t)t * 4096 + k * 256 + tid] = bf16_rne(ov * fast_tanh(c_st));
        }
        __syncthreads();  // drains the Hg stores (vmcnt(0) before s_barrier) + gl reads done
        if (tid == 0)
            __hip_atomic_fetch_add(&cnt[t], 1, __ATOMIC_RELEASE, __HIP_MEMORY_SCOPE_AGENT);
        xv = xnext;
    }
}

// feats[b][t][tag] = h(b,t) . W_out[tag] + b_out[tag].  2048 blocks x 256, wave = one (b,t).
__global__ __launch_bounds__(256) void feats_k(const unsigned short* __restrict__ Hg,
                                               const float* __restrict__ W_out,
                                               const float* __restrict__ b_out,
                                               float* __restrict__ feats) {
    int wid = blockIdx.x * 4 + (threadIdx.x >> 6);
    int l = threadIdx.x & 63;
    int b = wid >> 9, t = wid & 511;
    // lane l covers u = (l>>2)*16 + (l&3)*4 + {0..3}; Hg layout [t][ks][b][ul]
    uint2 hv = *(const uint2*)(Hg + (size_t)t * 4096 + (l >> 2) * 256 + b * 16 + (l & 3) * 4);
    float h0 = __builtin_bit_cast(float, (hv.x & 0xffffu) << 16);
    float h1 = __builtin_bit_cast(float, hv.x & 0xffff0000u);
    float h2 = __builtin_bit_cast(float, (hv.y & 0xffffu) << 16);
    float h3 = __builtin_bit_cast(float, hv.y & 0xffff0000u);
    int ub = (l >> 2) * 16 + (l & 3) * 4;
#pragma unroll
    for (int tag = 0; tag < 6; tag++) {
        float4 w = *(const float4*)(W_out + tag * 256 + ub);
        float p = h0 * w.x + h1 * w.y + h2 * w.z + h3 * w.w;
#pragma unroll
        for (int off = 32; off; off >>= 1) p += __shfl_down(p, off);
        if (l == 0) feats[((size_t)b * 512 + t) * 6 + tag] = p + b_out[tag];
    }
}

// 16 blocks x 64 threads. Lane nx owns next-tag nx; fv broadcast via shfl each step.
__global__ __launch_bounds__(64) void crf_scan(const float* __restrict__ feats,
                                               const float* __restrict__ trans,
                                               float* __restrict__ out) {
    __shared__ float fl[T * 6];
    __shared__ unsigned char bp[T * 8];
    int b = blockIdx.x, tid = threadIdx.x;
    const float4* src = (const float4*)(feats + (size_t)b * 3072);
#pragma unroll
    for (int i = 0; i < 12; i++) ((float4*)fl)[tid + i * 64] = src[tid + i * 64];
    int nx = (tid < 6) ? tid : 0;
    float tr0 = trans[nx * 6 + 0], tr1 = trans[nx * 6 + 1], tr2 = trans[nx * 6 + 2],
          tr3 = trans[nx * 6 + 3], tr4 = trans[nx * 6 + 4], tr5 = trans[nx * 6 + 5];
    float fv0 = NEGV, fv1 = NEGV, fv2 = NEGV, fv3 = NEGV, fv4 = 0.f, fv5 = NEGV;  // START=4
    __syncthreads();
    for (int t = 0; t < T; t++) {
        float best = fv0 + tr0; int arg = 0; float s;
        s = fv1 + tr1; if (s > best) { best = s; arg = 1; }
        s = fv2 + tr2; if (s > best) { best = s; arg = 2; }
        s = fv3 + tr3; if (s > best) { best = s; arg = 3; }
        s = fv4 + tr4; if (s > best) { best = s; arg = 4; }
        s = fv5 + tr5; if (s > best) { best = s; arg = 5; }  // strict >: first-max
        float nf = best + fl[t * 6 + nx];
        if (tid < 6) bp[t * 8 + tid] = (unsigned char)arg;
        fv0 = __shfl(nf, 0); fv1 = __shfl(nf, 1); fv2 = __shfl(nf, 2);
        fv3 = __shfl(nf, 3); fv4 = __shfl(nf, 4); fv5 = __shfl(nf, 5);
    }
    __syncthreads();
    if (tid == 0) {
        float best = fv0 + trans[STOP * 6 + 0]; int arg = 0; float s;
        s = fv1 + trans[STOP * 6 + 1]; if (s > best) { best = s; arg = 1; }
        s = fv2 + trans[STOP * 6 + 2]; if (s > best) { best = s; arg = 2; }
        s = fv3 + trans[STOP * 6 + 3]; if (s > best) { best = s; arg = 3; }
        s = fv4 + trans[STOP * 6 + 4]; if (s > best) { best = s; arg = 4; }
        s = fv5 + trans[STOP * 6 + 5]; if (s > best) { best = s; arg = 5; }
        out[b] = best;
        int tag = arg;
        float* paths = out + 16 + (size_t)b * 512;
        for (int t = T - 1; t >= 0; t--) {
            paths[t] = (float)tag;
            tag = bp[t * 8 + tag];
        }
    }
}

extern "C" void kernel_launch(void* const* d_in, const int* in_sizes, int n_in,
                              void* d_out, int out_size, void* d_ws, size_t ws_size,
                              hipStream_t stream) {
    const int* sentence = (const int*)d_in[0];
    const float* embedding = (const float*)d_in[1];
    const float* W_ih = (const float*)d_in[2];
    const float* W_hh = (const float*)d_in[3];
    const float* b_ih = (const float*)d_in[4];
    const float* b_hh = (const float*)d_in[5];
    const float* W_out = (const float*)d_in[6];
    const float* b_out = (const float*)d_in[7];
    const float* trans = (const float*)d_in[8];
    float* out = (float*)d_out;
    float* ws = (float*)d_ws;

    float* Xp2 = ws;
    unsigned short* Hg = (unsigned short*)ws;               // aliases Xp2 (8x trail, safe)
    float* WihT = ws + 8388608;
    unsigned short* Wf = (unsigned short*)(ws + 8650752);
    float* feats = ws + 8781824;
    int* cnt = (int*)(ws + 8830976);

    hipLaunchKernelGGL(transpose_wih, dim3(1024), dim3(256), 0, stream, W_ih, WihT, cnt);
    hipLaunchKernelGGL(input_proj, dim3(BATCH * T / 16), dim3(1024), 0, stream,
                       sentence, embedding, WihT, b_ih, b_hh, Xp2);
    hipLaunchKernelGGL(wf_prep, dim3(128), dim3(256), 0, stream, W_hh, Wf);
    hipLaunchKernelGGL(lstm_mfma, dim3(NBLK), dim3(256), 0, stream, Wf, Xp2, Hg, cnt);
    hipLaunchKernelGGL(feats_k, dim3(2048), dim3(256), 0, stream, Hg, W_out, b_out, feats);
    hipLaunchKernelGGL(crf_scan, dim3(BATCH), dim3(64), 0, stream, feats, trans, out);
}

// Round 6
// 1130.148 us; speedup vs baseline: 8.9246x; 1.1784x over previous
//
#include <hip/hip_runtime.h>
#include <math.h>

#define HDIM 256
#define BATCH 16
#define T 512
#define NT 6
#define START 4
#define STOP 5
#define NEGV -10000.0f
#define LOG2E 1.4426950408889634f
#define NBLK 16  // lstm blocks; block k owns gate cols {n*256 + k*16 + c}

typedef __attribute__((ext_vector_type(8))) short short8;
typedef __attribute__((ext_vector_type(4))) float f32x4;

union U16B { unsigned long long u[2]; short8 s; };
union UPK { unsigned short s[4]; unsigned long long u; };

__device__ __forceinline__ float fast_sig(float x) {
    float e = __builtin_amdgcn_exp2f(-LOG2E * x);
    return __builtin_amdgcn_rcpf(1.f + e);
}
__device__ __forceinline__ float fast_tanh(float x) {
    float e = __builtin_amdgcn_exp2f(-2.f * LOG2E * x);
    return (1.f - e) * __builtin_amdgcn_rcpf(1.f + e);
}
__device__ __forceinline__ unsigned short bf16_rne(float f) {
    unsigned u = __builtin_bit_cast(unsigned, f);
    u += 0x7FFFu + ((u >> 16) & 1u);
    return (unsigned short)(u >> 16);
}

// ws layout (float units):
//   [0, 8388608)            Xp2 fp32 [t][k][n][lane][j]   (32 MB)
//                           ... Hg bf16 [t][k][b][ul] aliases base (4 MB): Hg[t] writes
//                           (8KB/step) trail Xp2[t] reads (64KB/step) by 8x -> never clobber.
//   [8388608, 8650752)      WihT fp32 (dead after input_proj; Xp prefetch overruns here: benign)
//   [8650752, 8781824)      Wf bf16 MFMA B-fragments (512 KB)
//   [8781824, 8830976)      feats fp32 [b][t][6]
//   [8830976, 8831488)      flags int[512] (per-block step flags, 64B stride, zeroed each call)

__global__ void transpose_wih(const float* __restrict__ W_ih, float* __restrict__ WihT,
                              int* __restrict__ flags) {
    int o = blockIdx.x * blockDim.x + threadIdx.x;
    if (o < 512) flags[o] = 0;
    if (o >= 256 * 1024) return;
    int k = o >> 10;
    int g = o & 1023;
    WihT[o] = W_ih[g * 256 + k];
}

// Pack W_hh (fp32 [1024][256]) into bf16 MFMA B-fragments.
// flat frag f = ((k*4+n)*8+kt); lane l: g = n*256 + k*16 + (l&15), kk = kt*32 + (l>>4)*8 + j
__global__ void wf_prep(const float* __restrict__ W_hh, unsigned short* __restrict__ Wf) {
    int t = blockIdx.x * 256 + threadIdx.x;  // 0..32767
    int l = t & 63, kt = (t >> 6) & 7, n = (t >> 9) & 3, w = t >> 11;
    int g = n * 256 + w * 16 + (l & 15);
    int kk = kt * 32 + (l >> 4) * 8;
    const float* src = W_hh + g * 256 + kk;
    unsigned short* dst = Wf + (size_t)t * 8;
#pragma unroll
    for (int j = 0; j < 8; j++) dst[j] = bf16_rne(src[j]);
}

// One block = 16 (b,t) rows (same b, 16 consecutive t), 1024 threads = 1 per gate.
// Writes Xp2 in the MFMA C-layout: [t][k][n][lane=q*16+c][j] fp32.
__global__ __launch_bounds__(1024) void input_proj(const int* __restrict__ sentence,
                                                   const float* __restrict__ embedding,
                                                   const float* __restrict__ WihT,
                                                   const float* __restrict__ b_ih,
                                                   const float* __restrict__ b_hh,
                                                   float* __restrict__ Xp2) {
    __shared__ __align__(16) float emb[16][260];
    int tid = threadIdx.x;
    int bt0 = blockIdx.x * 16;
    {
        int r = tid >> 6, j = tid & 63;
        int row = sentence[bt0 + r];
        const float4* src = (const float4*)(embedding + (size_t)row * 256);
        float4 v = src[j];
        float* dst = &emb[r][j * 4];
        dst[0] = v.x; dst[1] = v.y; dst[2] = v.z; dst[3] = v.w;
    }
    __syncthreads();
    int g = tid;
    float bias = b_ih[g] + b_hh[g];
    float acc[16];
#pragma unroll
    for (int r = 0; r < 16; r++) acc[r] = bias;
    const float* wp = WihT + g;
    for (int k4 = 0; k4 < 64; k4++) {
        float w0 = wp[(k4 * 4 + 0) * 1024];
        float w1 = wp[(k4 * 4 + 1) * 1024];
        float w2 = wp[(k4 * 4 + 2) * 1024];
        float w3 = wp[(k4 * 4 + 3) * 1024];
#pragma unroll
        for (int r = 0; r < 16; r++) {
            float4 e = *(const float4*)&emb[r][k4 * 4];
            acc[r] += w0 * e.x + w1 * e.y + w2 * e.z + w3 * e.w;
        }
    }
    int b = bt0 >> 9, t0 = bt0 & 511;
    int q = b >> 2, j = b & 3;
    int n = g >> 8, u = g & 255, k = u >> 4, cc = u & 15;
    int lane = q * 16 + cc;
#pragma unroll
    for (int r = 0; r < 16; r++) {
        int t = t0 + r;
        Xp2[(size_t)(((t * 16 + k) * 4 + n) * 64 + lane) * 4 + j] = acc[r];
    }
}

// 16 blocks x 256 threads. Block k owns 64 gate columns (wave n = gate type, 16 cols).
// Cross-block h exchange via LLC-coherent (agent-scope relaxed, sc1) loads/stores —
// NO acquire/release cache flushes. Per-block padded flags instead of a counter.
__global__ __launch_bounds__(256) void lstm_mfma(const unsigned short* __restrict__ Wf,
                                                 const float* __restrict__ Xp2,
                                                 unsigned short* __restrict__ Hg,
                                                 int* __restrict__ flags) {
    __shared__ float gl[4][16][16];
    int tid = threadIdx.x;
    int k = blockIdx.x;
    int n = tid >> 6;          // wave = gate type (i,f,g,o)
    int l = tid & 63;
    int q = l >> 4;

    // B-fragments of this block's W_hh slice: 8 x short8 = 32 VGPR
    short8 wr[8];
#pragma unroll
    for (int kt = 0; kt < 8; kt++)
        wr[kt] = *(const short8*)(Wf + ((size_t)((k * 4 + n) * 8 + kt) * 64 + l) * 8);

    const char* xbase = (const char*)Xp2 + ((size_t)k * 4 + n) * 1024 + (size_t)l * 16;
    f32x4 xv = *(const f32x4*)xbase;

    // A-frag base within Hg[t] (ull units): row b=(l&15), u = kt*32 + q*8 + j
    // Hg layout [t][ks][b][ul]: ushort addr = ks*256 + b*16 + ul -> /4 for ull index
    int abase_us = (q >> 1) * 256 + (l & 15) * 16 + (q & 1) * 8;
    int abase_ull = abase_us >> 2;

    // c-state: threads 0..63 own 4 h/c values each: b = tid>>2, ul0 = (tid&3)*4
    float c_st[4] = {0.f, 0.f, 0.f, 0.f};
    int b_own = tid >> 2, ul0 = (tid & 3) * 4;

    int* myflag = flags + k * 16;
    int* spinflag = flags + (l & 15) * 16;

    for (int t = 0; t < T; t++) {
        f32x4 xnext = xv;
        if (t + 1 < T) xnext = *(const f32x4*)(xbase + (size_t)(t + 1) * 65536);
        f32x4 acc = xv;
        if (t > 0) {
            // all threads spin: lane l watches flags[l&15]; exit when all >= t
            while (true) {
                int f = __hip_atomic_load(spinflag, __ATOMIC_RELAXED, __HIP_MEMORY_SCOPE_AGENT);
                if (__all(f >= t)) break;
            }
            __builtin_amdgcn_fence(__ATOMIC_ACQUIRE, "workgroup");  // compiler ordering; no L2 inv
            const unsigned long long* hsrc =
                (const unsigned long long*)(Hg + (size_t)(t - 1) * 4096) + abase_ull;
            short8 af[8];
#pragma unroll
            for (int kt = 0; kt < 8; kt++) {
                U16B cv;
                cv.u[0] = __hip_atomic_load(hsrc + kt * 128 + 0, __ATOMIC_RELAXED,
                                            __HIP_MEMORY_SCOPE_AGENT);
                cv.u[1] = __hip_atomic_load(hsrc + kt * 128 + 1, __ATOMIC_RELAXED,
                                            __HIP_MEMORY_SCOPE_AGENT);
                af[kt] = cv.s;
            }
#pragma unroll
            for (int kt = 0; kt < 8; kt++)
                acc = __builtin_amdgcn_mfma_f32_16x16x32_bf16(af[kt], wr[kt], acc, 0, 0, 0);
        }
        // exchange gates across waves: lane (q,c) reg j -> (b=q*4+j, col c), gate n
        {
            int c = l & 15;
#pragma unroll
            for (int j = 0; j < 4; j++) gl[n][q * 4 + j][c] = acc[j];
        }
        __syncthreads();  // A: gates ready
        if (tid < 64) {
            UPK pk;
#pragma unroll
            for (int j = 0; j < 4; j++) {
                float iv = fast_sig(gl[0][b_own][ul0 + j]);
                float fg = fast_sig(gl[1][b_own][ul0 + j]);
                float gv = fast_tanh(gl[2][b_own][ul0 + j]);
                float ov = fast_sig(gl[3][b_own][ul0 + j]);
                c_st[j] = fg * c_st[j] + iv * gv;
                pk.s[j] = bf16_rne(ov * fast_tanh(c_st[j]));
            }
            // LLC-direct h publish (8B covers 4 h values)
            __hip_atomic_store((unsigned long long*)(Hg + (size_t)t * 4096 + k * 256) + tid,
                               pk.u, __ATOMIC_RELAXED, __HIP_MEMORY_SCOPE_AGENT);
        }
        __syncthreads();  // B: drains vmcnt -> h stores acked at LLC; gl reads done
        if (tid == 0)
            __hip_atomic_store(myflag, t + 1, __ATOMIC_RELAXED, __HIP_MEMORY_SCOPE_AGENT);
        xv = xnext;
    }
}

// feats[b][t][tag] = h(b,t) . W_out[tag] + b_out[tag].  2048 blocks x 256, wave = one (b,t).
__global__ __launch_bounds__(256) void feats_k(const unsigned short* __restrict__ Hg,
                                               const float* __restrict__ W_out,
                                               const float* __restrict__ b_out,
                                               float* __restrict__ feats) {
    int wid = blockIdx.x * 4 + (threadIdx.x >> 6);
    int l = threadIdx.x & 63;
    int b = wid >> 9, t = wid & 511;
    uint2 hv = *(const uint2*)(Hg + (size_t)t * 4096 + (l >> 2) * 256 + b * 16 + (l & 3) * 4);
    float h0 = __builtin_bit_cast(float, (hv.x & 0xffffu) << 16);
    float h1 = __builtin_bit_cast(float, hv.x & 0xffff0000u);
    float h2 = __builtin_bit_cast(float, (hv.y & 0xffffu) << 16);
    float h3 = __builtin_bit_cast(float, hv.y & 0xffff0000u);
    int ub = (l >> 2) * 16 + (l & 3) * 4;
#pragma unroll
    for (int tag = 0; tag < 6; tag++) {
        float4 w = *(const float4*)(W_out + tag * 256 + ub);
        float p = h0 * w.x + h1 * w.y + h2 * w.z + h3 * w.w;
#pragma unroll
        for (int off = 32; off; off >>= 1) p += __shfl_down(p, off);
        if (l == 0) feats[((size_t)b * 512 + t) * 6 + tag] = p + b_out[tag];
    }
}

// 16 blocks x 64 threads. Lane nx owns next-tag nx; fv broadcast via shfl each step.
__global__ __launch_bounds__(64) void crf_scan(const float* __restrict__ feats,
                                               const float* __restrict__ trans,
                                               float* __restrict__ out) {
    __shared__ float fl[T * 6];
    __shared__ unsigned char bp[T * 8];
    int b = blockIdx.x, tid = threadIdx.x;
    const float4* src = (const float4*)(feats + (size_t)b * 3072);
#pragma unroll
    for (int i = 0; i < 12; i++) ((float4*)fl)[tid + i * 64] = src[tid + i * 64];
    int nx = (tid < 6) ? tid : 0;
    float tr0 = trans[nx * 6 + 0], tr1 = trans[nx * 6 + 1], tr2 = trans[nx * 6 + 2],
          tr3 = trans[nx * 6 + 3], tr4 = trans[nx * 6 + 4], tr5 = trans[nx * 6 + 5];
    float fv0 = NEGV, fv1 = NEGV, fv2 = NEGV, fv3 = NEGV, fv4 = 0.f, fv5 = NEGV;  // START=4
    __syncthreads();
    for (int t = 0; t < T; t++) {
        float best = fv0 + tr0; int arg = 0; float s;
        s = fv1 + tr1; if (s > best) { best = s; arg = 1; }
        s = fv2 + tr2; if (s > best) { best = s; arg = 2; }
        s = fv3 + tr3; if (s > best) { best = s; arg = 3; }
        s = fv4 + tr4; if (s > best) { best = s; arg = 4; }
        s = fv5 + tr5; if (s > best) { best = s; arg = 5; }  // strict >: first-max
        float nf = best + fl[t * 6 + nx];
        if (tid < 6) bp[t * 8 + tid] = (unsigned char)arg;
        fv0 = __shfl(nf, 0); fv1 = __shfl(nf, 1); fv2 = __shfl(nf, 2);
        fv3 = __shfl(nf, 3); fv4 = __shfl(nf, 4); fv5 = __shfl(nf, 5);
    }
    __syncthreads();
    if (tid == 0) {
        float best = fv0 + trans[STOP * 6 + 0]; int arg = 0; float s;
        s = fv1 + trans[STOP * 6 + 1]; if (s > best) { best = s; arg = 1; }
        s = fv2 + trans[STOP * 6 + 2]; if (s > best) { best = s; arg = 2; }
        s = fv3 + trans[STOP * 6 + 3]; if (s > best) { best = s; arg = 3; }
        s = fv4 + trans[STOP * 6 + 4]; if (s > best) { best = s; arg = 4; }
        s = fv5 + trans[STOP * 6 + 5]; if (s > best) { best = s; arg = 5; }
        out[b] = best;
        int tag = arg;
        float* paths = out + 16 + (size_t)b * 512;
        for (int t = T - 1; t >= 0; t--) {
            paths[t] = (float)tag;
            tag = bp[t * 8 + tag];
        }
    }
}

extern "C" void kernel_launch(void* const* d_in, const int* in_sizes, int n_in,
                              void* d_out, int out_size, void* d_ws, size_t ws_size,
                              hipStream_t stream) {
    const int* sentence = (const int*)d_in[0];
    const float* embedding = (const float*)d_in[1];
    const float* W_ih = (const float*)d_in[2];
    const float* W_hh = (const float*)d_in[3];
    const float* b_ih = (const float*)d_in[4];
    const float* b_hh = (const float*)d_in[5];
    const float* W_out = (const float*)d_in[6];
    const float* b_out = (const float*)d_in[7];
    const float* trans = (const float*)d_in[8];
    float* out = (float*)d_out;
    float* ws = (float*)d_ws;

    float* Xp2 = ws;
    unsigned short* Hg = (unsigned short*)ws;               // aliases Xp2 (8x trail, safe)
    float* WihT = ws + 8388608;
    unsigned short* Wf = (unsigned short*)(ws + 8650752);
    float* feats = ws + 8781824;
    int* flags = (int*)(ws + 8830976);

    hipLaunchKernelGGL(transpose_wih, dim3(1024), dim3(256), 0, stream, W_ih, WihT, flags);
    hipLaunchKernelGGL(input_proj, dim3(BATCH * T / 16), dim3(1024), 0, stream,
                       sentence, embedding, WihT, b_ih, b_hh, Xp2);
    hipLaunchKernelGGL(wf_prep, dim3(128), dim3(256), 0, stream, W_hh, Wf);
    hipLaunchKernelGGL(lstm_mfma, dim3(NBLK), dim3(256), 0, stream, Wf, Xp2, Hg, flags);
    hipLaunchKernelGGL(feats_k, dim3(2048), dim3(256), 0, stream, Hg, W_out, b_out, feats);
    hipLaunchKernelGGL(crf_scan, dim3(BATCH), dim3(64), 0, stream, feats, trans, out);
}